// Round 1
// baseline (124.886 us; speedup 1.0000x reference)
//
#include <hip/hip_runtime.h>

// Input indices (setup_inputs() dict order):
//  0:x 1:W1 2:b1 3:gn1_g 4:gn1_b 5:W2 6:b2 7:W3 8:b3 9:gn2_g 10:gn2_b
//  11:fc1_W[16384,512] 12:fc1_b[512] 13:fc2_W[512,128] 14:fc2_b[128]
//  15:wc_W[128] 16:wc_b[1] 17:sel_W[128] 18:sel_b[1]
//
// Math note: groups==C in both GroupNorms -> per-group var==0 exactly ->
// output == beta exactly (0 * rsqrt(eps) * gamma + beta). So the whole conv
// front-end is dead; flat[k] = relu(gn2_b[k>>8]) for all batch rows, and the
// two outputs are two scalars replicated 128x each.

#define ROWS_PER_BLOCK 64  // 16384 rows / 64 = 256 blocks; 64 | 256 so one channel per block

__global__ __launch_bounds__(512) void fc1_reduce_kernel(
    const float* __restrict__ fc1_W,   // [16384, 512] row-major
    const float* __restrict__ gn2_b,   // [64]
    float* __restrict__ y1acc)         // [512] pre-zeroed accumulator
{
    const int j   = threadIdx.x;          // column 0..511
    const int bid = blockIdx.x;           // 0..255
    const int row0 = bid * ROWS_PER_BLOCK;

    // channel is constant for the whole block: (bid*64 + r) >> 8 == bid >> 2
    float vc = gn2_b[bid >> 2];
    vc = vc > 0.0f ? vc : 0.0f;

    const float* p = fc1_W + (size_t)row0 * 512 + j;
    float acc = 0.0f;
#pragma unroll
    for (int r = 0; r < ROWS_PER_BLOCK; ++r) {
        acc += p[(size_t)r * 512];
    }
    atomicAdd(&y1acc[j], vc * acc);
}

__global__ __launch_bounds__(512) void tail_kernel(
    const float* __restrict__ y1acc,   // [512]
    const float* __restrict__ fc1_b,   // [512]
    const float* __restrict__ fc2_W,   // [512,128] row-major
    const float* __restrict__ fc2_b,   // [128]
    const float* __restrict__ wc_W,    // [128]
    const float* __restrict__ wc_b,    // [1]
    const float* __restrict__ sel_W,   // [128]
    const float* __restrict__ sel_b,   // [1]
    float* __restrict__ out)           // [256]: wc[128] then sel[128]
{
    __shared__ float y1s[512];
    __shared__ float part[512];
    __shared__ float redwc[128];
    __shared__ float redsel[128];
    __shared__ float scal[2];

    const int t = threadIdx.x;

    // y1 = relu(y1acc + fc1_b)
    float y1 = y1acc[t] + fc1_b[t];
    y1s[t] = y1 > 0.0f ? y1 : 0.0f;
    __syncthreads();

    // fc2: 4 threads per output column; column j = t&127, quarter q = t>>7
    const int j = t & 127;
    const int q = t >> 7;
    float acc = 0.0f;
    const int i0 = q * 128;
#pragma unroll 8
    for (int i = 0; i < 128; ++i) {
        acc += y1s[i0 + i] * fc2_W[(size_t)(i0 + i) * 128 + j];
    }
    part[t] = acc;
    __syncthreads();

    if (t < 128) {
        float y2 = part[t] + part[128 + t] + part[256 + t] + part[384 + t] + fc2_b[t];
        y2 = y2 > 0.0f ? y2 : 0.0f;
        redwc[t]  = y2 * wc_W[t];
        redsel[t] = y2 * sel_W[t];
    }
    __syncthreads();

    if (t == 0) {
        float s0 = 0.0f, s1 = 0.0f;
        for (int i = 0; i < 128; ++i) { s0 += redwc[i]; s1 += redsel[i]; }
        scal[0] = s0 + wc_b[0];
        scal[1] = s1 + sel_b[0];
    }
    __syncthreads();

    if (t < 128) {
        out[t]       = scal[0];  // wc head, replicated over batch
        out[128 + t] = scal[1];  // sel head, replicated over batch
    }
}

extern "C" void kernel_launch(void* const* d_in, const int* in_sizes, int n_in,
                              void* d_out, int out_size, void* d_ws, size_t ws_size,
                              hipStream_t stream) {
    (void)in_sizes; (void)n_in; (void)out_size; (void)ws_size;

    const float* gn2_b = (const float*)d_in[10];
    const float* fc1_W = (const float*)d_in[11];
    const float* fc1_b = (const float*)d_in[12];
    const float* fc2_W = (const float*)d_in[13];
    const float* fc2_b = (const float*)d_in[14];
    const float* wc_W  = (const float*)d_in[15];
    const float* wc_b  = (const float*)d_in[16];
    const float* sel_W = (const float*)d_in[17];
    const float* sel_b = (const float*)d_in[18];

    float* y1acc = (float*)d_ws;   // 512 floats
    float* out   = (float*)d_out;  // 256 floats

    // ws is poisoned with 0xAA before every launch -> zero the accumulator.
    hipMemsetAsync(y1acc, 0, 512 * sizeof(float), stream);

    fc1_reduce_kernel<<<256, 512, 0, stream>>>(fc1_W, gn2_b, y1acc);

    tail_kernel<<<1, 512, 0, stream>>>(y1acc, fc1_b, fc2_W, fc2_b,
                                       wc_W, wc_b, sel_W, sel_b, out);
}